// Round 7
// baseline (348.146 us; speedup 1.0000x reference)
//
#include <hip/hip_runtime.h>
#include <cstdint>

// Problem constants (B,N,H,D fixed by setup_inputs)
#define BB 2
#define NN 2048
#define HH 16
#define DD 128
#define BH 32   // BB*HH
#define NPROJ 7

typedef __bf16 bf16x8 __attribute__((ext_vector_type(8)));
typedef float f32x4 __attribute__((ext_vector_type(4)));

__device__ __forceinline__ unsigned short f2bf(float f) {
  unsigned int u = __float_as_uint(f);
  u += 0x7fff + ((u >> 16) & 1);   // RN-even
  return (unsigned short)(u >> 16);
}

__device__ __forceinline__ bf16x8 load_q8(const float* p) {
  float4 a = *(const float4*)p;
  float4 b = *(const float4*)(p + 4);
  unsigned short r[8] = {f2bf(a.x), f2bf(a.y), f2bf(a.z), f2bf(a.w),
                         f2bf(b.x), f2bf(b.y), f2bf(b.z), f2bf(b.w)};
  return *(bf16x8*)r;
}

#if __has_builtin(__builtin_amdgcn_exp2f)
#define EXP2(x) __builtin_amdgcn_exp2f(x)
#else
#define EXP2(x) exp2f(x)
#endif

#define CEXPC 0.1275174316582815f   // 128^-0.5 * log2(e)
#define PSLOT 8320                  // floats per partial slot: 64*128 o + 64 m + 64 l

// ---------------------------------------------------------------------------
// 1) Fused: LSH hash of q and k rows (blocks < 4096) + V bf16 transpose to
//    [B,H,D,N] (blocks >= 4096). Hash: 8 lanes per row, fp64 accumulation.
//    The k-hash path also emits K in bf16 [B,H,N,D] (Kb).  (unchanged)
// ---------------------------------------------------------------------------
__global__ void prep_kernel(const float* __restrict__ q, const float* __restrict__ k,
                            const float* __restrict__ v, const float* __restrict__ pd,
                            int* __restrict__ qh, int* __restrict__ kh,
                            unsigned short* __restrict__ Vt, unsigned short* __restrict__ Kb) {
  __shared__ __align__(16) char smem[64 * 132 * 2];  // union: spd (3.5K) / tile (16.5K)
  if (blockIdx.x < 4096) {
    float* spd = (float*)smem;
    for (int i = threadIdx.x; i < DD * NPROJ; i += 256) spd[i] = pd[i];
    __syncthreads();
    long long gid = (long long)blockIdx.x * 256 + threadIdx.x;
    int part = (int)(gid & 7);
    long long row = gid >> 3;
    const long long NR = (long long)BB * NN * HH;
    int isk = row >= NR;
    long long r = isk ? row - NR : row;            // flat [b][n][h]
    const float* src = (isk ? k : q) + r * DD + part * 16;
    double acc[NPROJ];
    for (int p = 0; p < NPROJ; ++p) acc[p] = 0.0;
    __align__(16) unsigned short kb16[16];
    for (int d = 0; d < 16; d += 4) {
      float4 x = *(const float4*)(src + d);
      if (isk) {
        kb16[d + 0] = f2bf(x.x); kb16[d + 1] = f2bf(x.y);
        kb16[d + 2] = f2bf(x.z); kb16[d + 3] = f2bf(x.w);
      }
      int dbase = part * 16 + d;
      for (int p = 0; p < NPROJ; ++p) {
        acc[p] += (double)x.x * (double)spd[(dbase + 0) * NPROJ + p]
                + (double)x.y * (double)spd[(dbase + 1) * NPROJ + p]
                + (double)x.z * (double)spd[(dbase + 2) * NPROJ + p]
                + (double)x.w * (double)spd[(dbase + 3) * NPROJ + p];
      }
    }
    int b_ = (int)(r / (NN * HH));
    int rem = (int)(r % (NN * HH));
    int n_ = rem / HH, h_ = rem % HH;
    if (isk) {
      unsigned short* dst = Kb + (((long long)(b_ * HH + h_) * NN + n_) << 7) + part * 16;
      *(uint4*)dst = *(const uint4*)&kb16[0];
      *(uint4*)(dst + 8) = *(const uint4*)&kb16[8];
    }
    for (int off = 1; off < 8; off <<= 1)
      for (int p = 0; p < NPROJ; ++p) acc[p] += __shfl_xor(acc[p], off);
    if (part == 0) {
      int bin = 0;
      for (int p = 0; p < NPROJ; ++p) bin |= ((int)(acc[p] > 0.0)) << p;
      int hsh = bin ^ (bin >> 1);                  // _unit_hamming == Gray code
      (isk ? kh : qh)[((long long)b_ * HH + h_) * NN + n_] = hsh;
    }
  } else {
    unsigned short (*tile)[132] = (unsigned short(*)[132])smem;
    int blk = blockIdx.x - 4096;
    int bh = blk >> 5;
    int n0 = (blk & 31) * 64;
    int b = bh >> 4, h = bh & 15;
    for (int it = 0; it < 8; ++it) {
      int cid = it * 256 + threadIdx.x;
      int r = cid >> 5, d4 = (cid & 31) * 4;
      float4 x = *(const float4*)(v + (((long long)(b * NN + n0 + r) * HH + h) << 7) + d4);
      *(ushort4*)&tile[r][d4] = make_ushort4(f2bf(x.x), f2bf(x.y), f2bf(x.z), f2bf(x.w));
    }
    __syncthreads();
    for (int it = 0; it < 8; ++it) {
      int cid = it * 256 + threadIdx.x;
      int d = cid >> 4, n4 = (cid & 15) * 4;
      ushort4 y = make_ushort4(tile[n4 + 0][d], tile[n4 + 1][d], tile[n4 + 2][d], tile[n4 + 3][d]);
      *(ushort4*)(Vt + ((long long)bh * DD + d) * NN + n0 + n4) = y;
    }
  }
}

// ---------------------------------------------------------------------------
// 2) Stable counting sort of q_hash per (b,h) + fused keep computation.
//    1024 threads (8 segments x 128 bins).  (unchanged)
// ---------------------------------------------------------------------------
__global__ void sortkeep_kernel(const int* __restrict__ qh, const int* __restrict__ kh,
                                int* __restrict__ sidx, int* __restrict__ keep) {
  __shared__ int sh[NN];
  __shared__ int cnt[8][128];
  __shared__ int cum[128];
  __shared__ int kflag[2];
  int bh = blockIdx.x;
  const int* src = qh + (long long)bh * NN;
  for (int i = threadIdx.x; i < NN; i += 1024) sh[i] = src[i];
  if (threadIdx.x < 2) kflag[threadIdx.x] = 0;
  __syncthreads();
  int bin = threadIdx.x & 127, seg = threadIdx.x >> 7;   // seg 0..7
  int n0 = seg * (NN / 8);
  int c = 0;
  for (int n = n0; n < n0 + NN / 8; ++n) c += (sh[n] == bin);
  cnt[seg][bin] = c;
  __syncthreads();
  if (threadIdx.x == 0) {
    int run = 0;
    for (int t = 0; t < 128; ++t) {
      cum[t] = run;
      run += cnt[0][t] + cnt[1][t] + cnt[2][t] + cnt[3][t]
           + cnt[4][t] + cnt[5][t] + cnt[6][t] + cnt[7][t];
    }
  }
  __syncthreads();
  int pos = cum[bin];
  for (int s = 0; s < seg; ++s) pos += cnt[s][bin];
  int f0 = 0, f1 = 0;
  for (int n = n0; n < n0 + NN / 8; ++n)
    if (sh[n] == bin) {
      sidx[(long long)bh * NN + pos] = n;
      int match = (bin == kh[(long long)bh * NN + pos]);
      if (pos < 1024) f0 |= match; else f1 |= match;
      ++pos;
    }
  if (f0) atomicOr(&kflag[0], 1);
  if (f1) atomicOr(&kflag[1], 1);
  __syncthreads();
  if (threadIdx.x < 2) keep[bh * 2 + threadIdx.x] = kflag[threadIdx.x];
}

// ---------------------------------------------------------------------------
// 3) Flash attention over sorted Q.
//    Per-iteration structure = R4 (best measured: Pb round-trip, K=32 PV,
//    f2bf packing; raw-domain exp2 softmax). SPLIT-K for the tail: q-tiles
//    with qt >= split_qt are computed as two independent key-range chunks
//    (unnormalized partials to ws), merged by combine_kernel. Max serial
//    chain drops 32 -> ~17 iters. Heavy-first task order.
// ---------------------------------------------------------------------------
__global__ __launch_bounds__(256, 3)
void flash_kernel(const float* __restrict__ q, const unsigned short* __restrict__ Kb,
                  const unsigned short* __restrict__ Vt, const int* __restrict__ sidx,
                  const int* __restrict__ keep, float* __restrict__ out,
                  float* __restrict__ part, int split_qt) {
  __shared__ __align__(16) unsigned short Kt[64 * 136];   // keys x d (+8 pad)
  __shared__ __align__(16) unsigned short Vs[128 * 72];   // d x keys (+8 pad)
  __shared__ __align__(16) unsigned short Pb[4][16 * 72]; // per-wave q x keys

  int bh = blockIdx.x;              // 0..31 (fastest varying)
  int nsp = 32 - split_qt;
  int y = blockIdx.y;
  int qt, kb0, kb1, half;
  if (y < 2 * nsp) {                // split tasks, heavy qt first
    half = y & 1;
    qt = 31 - (y >> 1);
    int nk = qt + 1, mid = nk >> 1;
    kb0 = half ? mid : 0;
    kb1 = half ? nk : mid;
  } else {                          // unsplit tasks, heavy first
    half = -1;
    qt = split_qt - 1 - (y - 2 * nsp);
    kb0 = 0;
    kb1 = qt + 1;
  }
  int b = bh >> 4, h = bh & 15;
  int tid = threadIdx.x;
  int w = tid >> 6, lane = tid & 63;
  int l16 = lane & 15, qd = lane >> 4;

  const unsigned short* Kh = Kb + (long long)bh * NN * DD;
  const unsigned short* Vb = Vt + (long long)bh * DD * NN;

  // staging geometry: K tile 64x128 bf16 (16KB), V tile 128x64 bf16 (16KB)
  const int ksr = tid >> 4;          // K row base (+ it*16)
  const int ksc = (tid & 15) * 8;    // K col (ushort units)
  const int vsr = tid >> 3;          // V row base (+ it*32)
  const int vsc = (tid & 7) * 8;     // V col (ushort units)

  uint4 kreg[4], vreg[4];

#define STAGE_LOAD(K0, KP)                                                            \
  {                                                                                   \
    if (KP) {                                                                         \
      _Pragma("unroll")                                                               \
      for (int it = 0; it < 4; ++it)                                                  \
        kreg[it] = *(const uint4*)(Kh + (long long)((K0) + it * 16 + ksr) * DD + ksc);\
    } else {                                                                          \
      _Pragma("unroll")                                                               \
      for (int it = 0; it < 4; ++it) kreg[it] = make_uint4(0, 0, 0, 0);               \
    }                                                                                 \
    _Pragma("unroll")                                                                 \
    for (int it = 0; it < 4; ++it)                                                    \
      vreg[it] = *(const uint4*)(Vb + (long long)(it * 32 + vsr) * NN + (K0) + vsc);  \
  }

#define STAGE_WRITE()                                                                 \
  {                                                                                   \
    _Pragma("unroll")                                                                 \
    for (int it = 0; it < 4; ++it)                                                    \
      *(uint4*)&Kt[(it * 16 + ksr) * 136 + ksc] = kreg[it];                           \
    _Pragma("unroll")                                                                 \
    for (int it = 0; it < 4; ++it)                                                    \
      *(uint4*)&Vs[(it * 32 + vsr) * 72 + vsc] = vreg[it];                            \
  }

  int qrow = qt * 64 + w * 16 + l16;

  // Q fragments, gathered from fp32 q via sidx (once per block)
  bf16x8 qf[4];
  {
    int nq = sidx[bh * NN + qrow];
    const float* p0 = q + (((long long)(b * NN + nq) * HH + h) << 7) + qd * 8;
#pragma unroll
    for (int c = 0; c < 4; ++c) qf[c] = load_q8(p0 + c * 32);
  }
  f32x4 o[8];
#pragma unroll
  for (int i = 0; i < 8; ++i) o[i] = (f32x4){0.f, 0.f, 0.f, 0.f};
  float m = -__builtin_inff(), l = 0.f;

  // prologue: stage first tile (fresh LDS, no prior readers)
  STAGE_LOAD(kb0 * 64, keep[h * 4 + (kb0 >> 3)]);
  STAGE_WRITE();
  __syncthreads();

  for (int kb = kb0; kb < kb1; ++kb) {
    // issue next tile's global loads BEFORE compute (latency hides here)
    if (kb + 1 < kb1) STAGE_LOAD((kb + 1) * 64, keep[h * 4 + ((kb + 1) >> 3)]);

    int k0 = kb * 64;

    // --- S^T = K * Q^T (K fragments from LDS), RAW scores (no scale) ---
    float s[16];
    __builtin_amdgcn_s_setprio(1);
#pragma unroll
    for (int t = 0; t < 4; ++t) {
      f32x4 a1 = (f32x4){0.f, 0.f, 0.f, 0.f};
#pragma unroll
      for (int c = 0; c < 4; ++c) {
        bf16x8 kf = *(const bf16x8*)&Kt[(t * 16 + l16) * 136 + c * 32 + qd * 8];
        a1 = __builtin_amdgcn_mfma_f32_16x16x32_bf16(kf, qf[c], a1, 0, 0, 0);
      }
      if (kb == qt) {              // causal mask only on the diagonal tile
#pragma unroll
        for (int r = 0; r < 4; ++r) {
          int keyg = k0 + t * 16 + qd * 4 + r;
          s[t * 4 + r] = (keyg > qrow) ? -__builtin_inff() : a1[r];
        }
      } else {
#pragma unroll
        for (int r = 0; r < 4; ++r) s[t * 4 + r] = a1[r];
      }
    }
    __builtin_amdgcn_s_setprio(0);

    // --- online softmax in raw-S domain (exp2-folded) ---
    {
      float x0 = fmaxf(fmaxf(s[0], s[1]), fmaxf(s[2], s[3]));
      float x1 = fmaxf(fmaxf(s[4], s[5]), fmaxf(s[6], s[7]));
      float x2 = fmaxf(fmaxf(s[8], s[9]), fmaxf(s[10], s[11]));
      float x3 = fmaxf(fmaxf(s[12], s[13]), fmaxf(s[14], s[15]));
      float mloc = fmaxf(fmaxf(x0, x1), fmaxf(x2, x3));
      mloc = fmaxf(mloc, __shfl_xor(mloc, 16));
      mloc = fmaxf(mloc, __shfl_xor(mloc, 32));
      if (__any(mloc > m)) {       // alpha==1 exactly when skipped
        float mnew = fmaxf(m, mloc);
        float alpha = EXP2((m - mnew) * CEXPC);
        float aO[4];
#pragma unroll
        for (int r = 0; r < 4; ++r) aO[r] = __shfl(alpha, qd * 4 + r);
#pragma unroll
        for (int c8 = 0; c8 < 8; ++c8)
#pragma unroll
          for (int r = 0; r < 4; ++r) o[c8][r] *= aO[r];
        l *= alpha;
        m = mnew;
      }
      float mc = m * CEXPC;
      float psum = 0.f;
#pragma unroll
      for (int t = 0; t < 4; ++t) {
        float p0 = EXP2(__builtin_fmaf(s[t * 4 + 0], CEXPC, -mc));
        float p1 = EXP2(__builtin_fmaf(s[t * 4 + 1], CEXPC, -mc));
        float p2 = EXP2(__builtin_fmaf(s[t * 4 + 2], CEXPC, -mc));
        float p3 = EXP2(__builtin_fmaf(s[t * 4 + 3], CEXPC, -mc));
        psum += (p0 + p1) + (p2 + p3);
        *(ushort4*)&Pb[w][l16 * 72 + t * 16 + qd * 4] =
            make_ushort4(f2bf(p0), f2bf(p1), f2bf(p2), f2bf(p3));
      }
      psum += __shfl_xor(psum, 16);
      psum += __shfl_xor(psum, 32);
      l += psum;
    }

    // --- O += P * V  (V fragments from LDS, K=32) ---
    __builtin_amdgcn_s_setprio(1);
#pragma unroll
    for (int g = 0; g < 2; ++g) {
      bf16x8 pf = *(const bf16x8*)&Pb[w][l16 * 72 + g * 32 + qd * 8];
#pragma unroll
      for (int c8 = 0; c8 < 8; ++c8) {
        bf16x8 vf = *(const bf16x8*)&Vs[(c8 * 16 + l16) * 72 + g * 32 + qd * 8];
        o[c8] = __builtin_amdgcn_mfma_f32_16x16x32_bf16(pf, vf, o[c8], 0, 0, 0);
      }
    }
    __builtin_amdgcn_s_setprio(0);

    // single LDS buffer: wait for all readers, then overwrite with next tile
    if (kb + 1 < kb1) {
      __syncthreads();
      STAGE_WRITE();
      __syncthreads();
    }
  }

  if (half >= 0) {
    // --- split task: write unnormalized partial (o, m_raw, l) ---
    float* ps = part + (long long)((bh * nsp + (qt - split_qt)) * 2 + half) * PSLOT;
#pragma unroll
    for (int r = 0; r < 4; ++r) {
      int row = w * 16 + qd * 4 + r;
      float* pr = ps + row * 128 + l16;
#pragma unroll
      for (int c8 = 0; c8 < 8; ++c8) pr[c8 * 16] = o[c8][r];
    }
    if (qd == 0) {
      int row = w * 16 + l16;
      ps[8192 + row] = m;
      ps[8256 + row] = l;
    }
  } else {
    // --- unsplit: normalize and scatter-unsort directly ---
    float lO[4];
    int nO[4];
#pragma unroll
    for (int r = 0; r < 4; ++r) {
      lO[r] = __shfl(l, qd * 4 + r);
      nO[r] = sidx[(long long)bh * NN + qt * 64 + w * 16 + qd * 4 + r];
    }
#pragma unroll
    for (int r = 0; r < 4; ++r) {
      float inv = 1.f / lO[r];
      float* ob = out + (((long long)(b * NN + nO[r]) * HH + h) << 7) + l16;
#pragma unroll
      for (int c8 = 0; c8 < 8; ++c8)
        ob[c8 * 16] = o[c8][r] * inv;
    }
  }
#undef STAGE_LOAD
#undef STAGE_WRITE
}

// ---------------------------------------------------------------------------
// 4) Combine the two split-K partials per (bh, qt>=split_qt): exact online-
//    softmax merge, normalize, scatter-unsort. One block per (bh, qi).
// ---------------------------------------------------------------------------
__global__ __launch_bounds__(256)
void combine_kernel(const float* __restrict__ part, const int* __restrict__ sidx,
                    float* __restrict__ out, int split_qt) {
  int nsp = 32 - split_qt;
  int bh = blockIdx.x & 31, qi = blockIdx.x >> 5;
  int qt = split_qt + qi;
  int b = bh >> 4, h = bh & 15;
  const float* p0 = part + (long long)((bh * nsp + qi) * 2 + 0) * PSLOT;
  const float* p1 = p0 + PSLOT;
  int row = threadIdx.x >> 2;           // 0..63
  int colg = (threadIdx.x & 3) * 32;    // 0,32,64,96
  float m0 = p0[8192 + row], l0 = p0[8256 + row];
  float m1 = p1[8192 + row], l1 = p1[8256 + row];
  float M = fmaxf(m0, m1);
  float a0 = EXP2((m0 - M) * CEXPC);
  float a1 = EXP2((m1 - M) * CEXPC);
  float inv = 1.f / (a0 * l0 + a1 * l1);
  float s0 = a0 * inv, s1 = a1 * inv;
  int nO = sidx[(long long)bh * NN + qt * 64 + row];
  float* ob = out + (((long long)(b * NN + nO) * HH + h) << 7) + colg;
  const float* r0 = p0 + row * 128 + colg;
  const float* r1 = p1 + row * 128 + colg;
#pragma unroll
  for (int c = 0; c < 32; c += 4) {
    float4 x0 = *(const float4*)(r0 + c);
    float4 x1 = *(const float4*)(r1 + c);
    float4 yv;
    yv.x = s0 * x0.x + s1 * x1.x;
    yv.y = s0 * x0.y + s1 * x1.y;
    yv.z = s0 * x0.z + s1 * x1.z;
    yv.w = s0 * x0.w + s1 * x1.w;
    *(float4*)(ob + c) = yv;
  }
}

// ---------------------------------------------------------------------------
// Workspace layout (bytes):
//   0        : q_hash   [B,H,N] int   (256 KiB)
//   256 KiB  : k_hash                 (256 KiB)
//   512 KiB  : sort_idx               (256 KiB)
//   768 KiB  : keep[64] int
//   2 MiB    : Vt bf16 [B,H,D,N]      (16 MiB)
//   18 MiB   : Kb bf16 [B,H,N,D]      (16 MiB)
//   34 MiB   : split-K partials (33280 B per slot, 2 slots per split tile)
// ---------------------------------------------------------------------------
extern "C" void kernel_launch(void* const* d_in, const int* in_sizes, int n_in,
                              void* d_out, int out_size, void* d_ws, size_t ws_size,
                              hipStream_t stream) {
  const float* q = (const float*)d_in[0];
  const float* k = (const float*)d_in[1];
  const float* v = (const float*)d_in[2];
  const float* pd = (const float*)d_in[3];
  float* out = (float*)d_out;
  char* ws = (char*)d_ws;
  int* qh   = (int*)(ws + 0);
  int* kh   = (int*)(ws + (1u << 18));
  int* sidx = (int*)(ws + (2u << 18));
  int* keep = (int*)(ws + 3u * (1u << 18));
  unsigned short* Vt = (unsigned short*)(ws + (2u << 20));
  unsigned short* Kb = (unsigned short*)(ws + (18u << 20));
  size_t pbase = 34ull << 20;
  float* part = (float*)(ws + pbase);

  // pick split threshold by available workspace (fallback: no split = R4 form)
  int split_qt;
  if (ws_size >= pbase + 32ull * 16 * 2 * (PSLOT * 4)) split_qt = 16;
  else if (ws_size >= pbase + 32ull * 8 * 2 * (PSLOT * 4)) split_qt = 24;
  else split_qt = 32;
  int nsp = 32 - split_qt;

  prep_kernel<<<5120, 256, 0, stream>>>(q, k, v, pd, qh, kh, Vt, Kb);
  sortkeep_kernel<<<32, 1024, 0, stream>>>(qh, kh, sidx, keep);
  flash_kernel<<<dim3(32, 2 * nsp + split_qt), 256, 0, stream>>>(
      q, Kb, Vt, sidx, keep, out, part, split_qt);
  if (nsp > 0)
    combine_kernel<<<32 * nsp, 256, 0, stream>>>(part, sidx, out, split_qt);
}